// Round 16
// baseline (3159.475 us; speedup 1.0000x reference)
//
#include <hip/hip_runtime.h>

typedef unsigned int uint;
typedef unsigned short u16;
typedef short s16x8 __attribute__((ext_vector_type(8)));
typedef float f32x4 __attribute__((ext_vector_type(4)));
typedef uint u32x4 __attribute__((ext_vector_type(4)));

#define MFMA16(a, b, c) __builtin_amdgcn_mfma_f32_16x16x32_bf16((a), (b), (c), 0, 0, 0)

// ---- problem constants ----
// B=64, S=512, D=512, H=512, L=2
// sync (8192 B reserve):
//   [xcc*128 + b*32], b=0..3 : per-XCD barrier counters b1A,b1B,b2A,b2B (own 128B lines)
//   [1024+xcc]               : claim[8]
//   [1088+q*32]              : prog[q] (own 128B line, L3 agent atomics)
// Exchange buffers: per (layer,quarter) COMPACT half-regions, 2-deep rotation.
//   A-half rows 0-7 live; B-half rows 8-15 live; dead MFMA rows read from WT (const).
static const size_t OFF_SYNC = 0;                      // 8192 B
static const size_t OFF_HBA  = 8192;                   // [2][4][2][8][512] bf16 = 131072
static const size_t OFF_HBB  = 139264;                 // 131072
static const size_t OFF_RHA  = 270336;                 // 131072
static const size_t OFF_RHB  = 401408;                 // 131072
static const size_t OFF_WT   = 532480;                 // [2][3][512][1024] bf16 = 6291456
static const size_t OFF_YS0  = 6823936;                // [64][512][512] bf16 = 33554432
static const size_t OFF_GX   = 40378368;               // [512][64][1536] f32 or bf16
static const size_t GX_ELEMS = (size_t)512 * 64 * 1536;

__device__ __forceinline__ short f2bf(float x) {       // RNE float->bf16
  uint u = __builtin_bit_cast(uint, x);
  u = u + 0x7fffu + ((u >> 16) & 1u);
  return (short)(u >> 16);
}
__device__ __forceinline__ float bf2f(u16 v) {
  uint u = ((uint)v) << 16;
  return __builtin_bit_cast(float, u);
}

// ---- raw memory ops ----
__device__ __forceinline__ u32x4 ld16(const void* p) {          // plain: L1 + local L2
  u32x4 r;
  asm volatile("global_load_dwordx4 %0, %1, off" : "=v"(r) : "v"(p));
  return r;
}
__device__ __forceinline__ uint ld4u(const void* p) {
  uint r;
  asm volatile("global_load_dword %0, %1, off" : "=v"(r) : "v"(p));
  return r;
}
__device__ __forceinline__ uint ld2x(const void* p) {
  uint r;
  asm volatile("global_load_ushort %0, %1, off" : "=v"(r) : "v"(p));
  return r;
}
__device__ __forceinline__ void st4(void* p, uint v) {
  asm volatile("global_store_dword %0, %1, off" :: "v"(p), "v"(v));
}
__device__ __forceinline__ void st2(void* p, u16 v) {
  uint x = v;
  asm volatile("global_store_short %0, %1, off" :: "v"(p), "v"(x));
}
// cross-XCD coherent (system scope, served at L3): sc0 sc1 — R3/R9-proven combo
__device__ __forceinline__ u32x4 ld16c(const void* p) {
  u32x4 r;
  asm volatile("global_load_dwordx4 %0, %1, off sc0 sc1" : "=v"(r) : "v"(p));
  return r;
}
__device__ __forceinline__ void st2c(void* p, u16 v) {
  uint x = v;
  asm volatile("global_store_short %0, %1, off sc0 sc1" :: "v"(p), "v"(x));
}
__device__ __forceinline__ void waitv0() {
  asm volatile("s_waitcnt vmcnt(0)" ::: "memory");
  __builtin_amdgcn_sched_barrier(0);   // rule #18
}

template <int GXBF>
__device__ __forceinline__ float upk(uint v) {
  if constexpr (GXBF) return bf2f((u16)v);
  else return __builtin_bit_cast(float, v);
}

// ---------------- sentinel ----------------
__global__ void sentinel_kernel(float* __restrict__ out, float v) {
  out[threadIdx.x] = v;
}

// ---------------- init: sync words, h0 -> compact half layouts (buf 0) ----------------
__global__ void init_kernel(const float* __restrict__ h_in, u16* __restrict__ hbA,
                            u16* __restrict__ hbB, int* __restrict__ sync) {
  int idx = blockIdx.x * 256 + threadIdx.x;
  if (idx < 2048) sync[idx] = 0;
  for (int i = idx; i < 2 * 64 * 512; i += gridDim.x * 256) {
    int l = i >> 15, b = (i >> 9) & 63, c = i & 511;
    int q = b >> 4, ob = b & 15;
    u16 v = (u16)f2bf(h_in[(b * 2 + l) * 512 + c]);
    int reg = ((l * 4 + q) * 2 + 0) * 4096;
    if (ob < 8) hbA[reg + ob * 512 + c] = v;
    else        hbB[reg + (ob - 8) * 512 + c] = v;
  }
}

// ---------------- W (L,1024,512) f32 -> WT[l][g][n][k] bf16 (k-major) ----------------
__global__ void convert_w_kernel(const float* __restrict__ Wr, const float* __restrict__ Wz,
                                 const float* __restrict__ Wh, u16* __restrict__ WT) {
  int idx = blockIdx.x * 256 + threadIdx.x;       // 6*512*1024 = 3145728 total
  int n = idx & 511, k = (idx >> 9) & 1023, lg = idx >> 19;
  int l = (lg >= 3) ? 1 : 0, g = lg - l * 3;
  const float* W = (g == 0 ? Wr : (g == 1 ? Wz : Wh)) + (size_t)l * 1024 * 512;
  WT[((size_t)lg * 512 + n) * 1024 + k] = (u16)f2bf(W[k * 512 + n]);
}

// ---------------- input projection GEMM (layer 0 only) ----------------
template <int GXBF>
__global__ __launch_bounds__(256) void proj_kernel(
    const float* __restrict__ A, const u16* __restrict__ WT,
    const float* __restrict__ br, const float* __restrict__ bz, const float* __restrict__ bh,
    void* __restrict__ gx) {
  __shared__ u16 Alds[128 * 64];
  __shared__ u16 Blds[128 * 64];
  const int tid = threadIdx.x;
  const int wave = tid >> 6, lane = tid & 63;
  const int lan15 = lane & 15, lanhi = lane >> 4;
  const int mb = blockIdx.x & 255, nb = blockIdx.x >> 8;
  const int m0 = mb * 128, n0 = nb * 128;
  const int wm = (wave >> 1) * 64, wn = (wave & 1) * 64;

  const f32x4 z4 = {0.f, 0.f, 0.f, 0.f};
  f32x4 acc[4][4];
#pragma unroll
  for (int i = 0; i < 4; ++i)
#pragma unroll
    for (int j = 0; j < 4; ++j) acc[i][j] = z4;

  for (int kb = 0; kb < 512; kb += 64) {
    __syncthreads();
#pragma unroll
    for (int p = 0; p < 4; ++p) {        // stage+convert A tile 128x64 (XOR-swizzled 16B slots)
      int idx = p * 256 + tid;
      int row = idx >> 3, slot = idx & 7;
      const float* src = A + (size_t)(m0 + row) * 512 + kb + slot * 8;
      float4 v0 = *(const float4*)src;
      float4 v1 = *(const float4*)(src + 4);
      u16 tmp[8] = {(u16)f2bf(v0.x), (u16)f2bf(v0.y), (u16)f2bf(v0.z), (u16)f2bf(v0.w),
                    (u16)f2bf(v1.x), (u16)f2bf(v1.y), (u16)f2bf(v1.z), (u16)f2bf(v1.w)};
      *(uint4*)((char*)Alds + row * 128 + ((slot ^ (row & 7)) * 16)) = *(uint4*)tmp;
    }
#pragma unroll
    for (int p = 0; p < 4; ++p) {        // stage B tile 128x64 from WT (n-major rows)
      int idx = p * 256 + tid;
      int row = idx >> 3, slot = idx & 7;
      int ng = n0 + row, g = ng >> 9, nc = ng & 511;
      uint4 v = *(const uint4*)(WT + ((size_t)g * 512 + nc) * 1024 + kb + slot * 8);
      *(uint4*)((char*)Blds + row * 128 + ((slot ^ (row & 7)) * 16)) = v;
    }
    __syncthreads();
#pragma unroll
    for (int ks = 0; ks < 2; ++ks) {
      s16x8 af[4], bfr[4];
#pragma unroll
      for (int f = 0; f < 4; ++f) {
        int rowA = wm + f * 16 + lan15;
        af[f] = *(const s16x8*)((const char*)Alds + rowA * 128 + (((ks * 4 + lanhi) ^ (rowA & 7)) * 16));
        int rowB = wn + f * 16 + lan15;
        bfr[f] = *(const s16x8*)((const char*)Blds + rowB * 128 + (((ks * 4 + lanhi) ^ (rowB & 7)) * 16));
      }
#pragma unroll
      for (int mf = 0; mf < 4; ++mf)
#pragma unroll
        for (int nf = 0; nf < 4; ++nf)
          acc[mf][nf] = MFMA16(af[mf], bfr[nf], acc[mf][nf]);
    }
  }
#pragma unroll
  for (int nf = 0; nf < 4; ++nf) {
    int n = n0 + wn + nf * 16 + lan15;
    int g = n >> 9, nc = n & 511;
    float bias = (g == 0 ? br[nc] : (g == 1 ? bz[nc] : bh[nc]));
#pragma unroll
    for (int mf = 0; mf < 4; ++mf) {
#pragma unroll
      for (int q = 0; q < 4; ++q) {
        int m = m0 + wm + mf * 16 + lanhi * 4 + q;
        int s = m & 511, b = m >> 9;
        size_t e = (size_t)(s * 64 + b) * 1536 + n;
        float v = acc[mf][nf][q] + bias;
        if constexpr (GXBF) ((u16*)gx)[e] = (u16)f2bf(v);
        else ((float*)gx)[e] = v;
      }
    }
  }
}

// ---------------- R14-proven barrier halves (contended returning-atomic poll) -----------
__device__ __forceinline__ void bar_arrive(int* bar) {
  asm volatile("s_waitcnt vmcnt(0)" ::: "memory");   // my publishes drained to L2/L3
  __syncthreads();
  if (threadIdx.x == 0) {
    int one = 1;
    asm volatile("global_atomic_add %0, %1, off" :: "v"(bar), "v"(one) : "memory");
  }
}
__device__ __forceinline__ void bar_wait(int* bar, int target) {
  if (threadIdx.x == 0) {
    int v, zero = 0, iter = 0;
    do {
      asm volatile("global_atomic_add %0, %1, %2, off sc0\n\ts_waitcnt vmcnt(0)"
                   : "=v"(v) : "v"(bar), "v"(zero) : "memory");
      if (v >= target) break;
      __builtin_amdgcn_s_sleep(1);
    } while (++iter < (1 << 17));      // watchdog: fail wrong, not hung
  }
  __syncthreads();
  __builtin_amdgcn_sched_barrier(0);
}

// red: [4 waves][48 cols][pad 20] f32
__device__ __forceinline__ int ROFF(int w, int c, int b) {
  return (w * 48 + c) * 20 + b;
}

// ---------------- persistent pipelined GRU: 8 XCDs = 2 layers x 4 batch-quarters ----------
// grid=256, 84KB LDS -> 1 WG/CU -> 32 WGs/XCD. layer = xcc>>2, quarter = xcc&3.
// NEW (this round): batch-halves A(0-7)/B(8-15) interleaved so every barrier wait is
// preceded by a half-phase of independent compute. 4 barriers/step (b1A,b1B,b2A,b2B),
// each R14-style. Half-regions are separate compact buffers (stale-L1-proof); dead MFMA
// rows read from the read-only WT region; 2-deep rotation.
template <int GXBF>
__global__ __launch_bounds__(256, 1) void gru_pipe(
    const void* __restrict__ gx,     // [512][64][1536] layer-0 gates
    const u16* __restrict__ WT,      // [2][3][512][1024]
    const float* __restrict__ h_in,  // [64][2][512]
    u16* __restrict__ hbA, u16* __restrict__ hbB,
    u16* __restrict__ rhA, u16* __restrict__ rhB,
    u16* __restrict__ ys0,           // [64][512][512] bf16 (L0 -> L1 via L3)
    const float* __restrict__ br, const float* __restrict__ bz, const float* __restrict__ bh,
    float* __restrict__ out_f32,     // d_out [64][512][512] f32
    float* __restrict__ finals,      // d_out + B*S*H  [64][2][512]
    int* __restrict__ sync) {
  __shared__ float red[21504];       // 84 KiB: forces 1 WG/CU
  __shared__ int s_pack, s_prog;

  if (threadIdx.x == 0) {
    int xcc;
    asm volatile("s_getreg_b32 %0, hwreg(HW_REG_XCC_ID)" : "=s"(xcc));
    xcc &= 7;
    int slot = __hip_atomic_fetch_add(&sync[1024 + xcc], 1, __ATOMIC_RELAXED,
                                      __HIP_MEMORY_SCOPE_AGENT);
    s_pack = slot | (xcc << 8);
    s_prog = 0;
  }
  __syncthreads();
  const int slot = s_pack & 255;
  const int xcc  = s_pack >> 8;
  if (slot >= 32) return;

  const int l = (xcc >> 2) & 1, q = xcc & 3;
  int* b1A = sync + xcc * 128;
  int* b1B = b1A + 32;
  int* b2A = b1A + 64;
  int* b2B = b1A + 96;
  int* prog = sync + 1088 + q * 32;

  const int tid = threadIdx.x;
  const int wave = tid >> 6, lane = tid & 63;
  const int lan15 = lane & 15, lanhi = lane >> 4;
  const int c0 = slot * 16;
  const int kw = wave * 128;
  const int ke8 = lanhi * 8;
  const int ob = tid >> 4;           // local batch 0..15
  const int col = c0 + (tid & 15);
  const int gb = q * 16 + ob;
  const bool isA = (ob < 8);         // wave-uniform (waves 0,1 = A; 2,3 = B)
  const int ES = GXBF ? 2 : 4;
  const f32x4 z4 = {0.f, 0.f, 0.f, 0.f};

  const u16* WTl = WT + (size_t)l * 3 * 512 * 1024;
  const u16* deadp = WT;             // read-only during pipe: safe garbage for dead rows
  const int reg2 = (l * 4 + q) * 2;  // *4096 + buf*4096
  u16* hbAq = hbA + reg2 * 4096;
  u16* hbBq = hbB + reg2 * 4096;
  u16* rhAq = rhA + reg2 * 4096;
  u16* rhBq = rhB + reg2 * 4096;

  // frag row base addresses (per-lane select once; k-offset added per load)
  // A-regions: rows 0-7 live; B-regions: rows 8-15 live.
  const int rowoff = lan15 * 512;
  const int rowoffB = (lan15 - 8) * 512;

  s16x8 wrz[2][4], whh[4];
#pragma unroll
  for (int g = 0; g < 2; ++g)
#pragma unroll
    for (int ks = 0; ks < 4; ++ks)
      wrz[g][ks] = *(const s16x8*)(WTl + ((size_t)(g * 512 + c0 + lan15)) * 1024 + 512 + kw + ks * 32 + ke8);
#pragma unroll
  for (int ks = 0; ks < 4; ++ks)
    whh[ks] = *(const s16x8*)(WTl + ((size_t)(1024 + c0 + lan15)) * 1024 + 512 + kw + ks * 32 + ke8);

  float hown = h_in[(gb * 2 + l) * 512 + col];

  if (l == 0) {
    // ======================= producer (layer 0) =======================
    uint pf_r = 0, pf_z = 0, pf_hn = 0, pf_hc = 0;
    auto issue_pf = [&](int tp) {
      const char* gq = (const char*)gx + ((size_t)(tp * 64 + gb) * 1536 + col) * ES;
      if constexpr (GXBF) {
        pf_r = ld2x(gq); pf_z = ld2x(gq + 512 * 2); pf_hn = ld2x(gq + 1024 * 2);
      } else {
        pf_r = ld4u(gq); pf_z = ld4u(gq + 512 * 4); pf_hn = ld4u(gq + 1024 * 4);
      }
    };
    issue_pf(0);
    float zg = 0.f, hn = 0.f;

    for (int t = 0; t < 512; ++t) {
      const int bufR = (t & 1) * 4096, bufW = ((t + 1) & 1) * 4096;
      // ---- P1A: r,z pre for half A ----
      {
        const u16* ha = (lan15 < 8) ? (hbAq + bufR + rowoff) : (deadp + rowoff);
        u32x4 hl[4];
#pragma unroll
        for (int ks = 0; ks < 4; ++ks) hl[ks] = ld16(ha + kw + ks * 32 + ke8);
        waitv0();                                // hl + pf(t) retired
        f32x4 a0 = z4, a1 = z4;
#pragma unroll
        for (int ks = 0; ks < 4; ++ks) {
          s16x8 ah = __builtin_bit_cast(s16x8, hl[ks]);
          a0 = MFMA16(ah, wrz[0][ks], a0);
          a1 = MFMA16(ah, wrz[1][ks], a1);
        }
        *(f32x4*)(red + ROFF(wave, lan15, lanhi * 4)) = a0;
        *(f32x4*)(red + ROFF(wave, 16 + lan15, lanhi * 4)) = a1;
        __syncthreads();
        if (isA) {
          float rp = upk<GXBF>(pf_r), zp = upk<GXBF>(pf_z);
#pragma unroll
          for (int w = 0; w < 4; ++w) {
            rp += red[ROFF(w, col - c0, ob)];
            zp += red[ROFF(w, 16 + (col - c0), ob)];
          }
          float r = 1.f / (1.f + __expf(-rp));
          zg = 1.f / (1.f + __expf(-zp));
          st2(rhAq + bufR + ob * 512 + col, (u16)f2bf(r * hown));
        }
      }
      bar_arrive(b1A);
      if (t > 0) {
        bar_wait(b2B, 32 * t);                   // hbB(t) ready; fill was P1A
        if (tid == 0 && slot == 0)               // step t-1 fully published
          __hip_atomic_fetch_add(prog, 1, __ATOMIC_RELAXED, __HIP_MEMORY_SCOPE_AGENT);
      }
      // ---- P1B ----
      {
        const u16* hbp = (lan15 >= 8) ? (hbBq + bufR + rowoffB) : (deadp + rowoff);
        u32x4 hl[4];
#pragma unroll
        for (int ks = 0; ks < 4; ++ks) hl[ks] = ld16(hbp + kw + ks * 32 + ke8);
        waitv0();
        f32x4 a0 = z4, a1 = z4;
#pragma unroll
        for (int ks = 0; ks < 4; ++ks) {
          s16x8 ah = __builtin_bit_cast(s16x8, hl[ks]);
          a0 = MFMA16(ah, wrz[0][ks], a0);
          a1 = MFMA16(ah, wrz[1][ks], a1);
        }
        *(f32x4*)(red + ROFF(wave, lan15, lanhi * 4)) = a0;
        *(f32x4*)(red + ROFF(wave, 16 + lan15, lanhi * 4)) = a1;
        __syncthreads();
        if (!isA) {
          float rp = upk<GXBF>(pf_r), zp = upk<GXBF>(pf_z);
#pragma unroll
          for (int w = 0; w < 4; ++w) {
            rp += red[ROFF(w, col - c0, ob)];
            zp += red[ROFF(w, 16 + (col - c0), ob)];
          }
          float r = 1.f / (1.f + __expf(-rp));
          zg = 1.f / (1.f + __expf(-zp));
          st2(rhBq + bufR + (ob - 8) * 512 + col, (u16)f2bf(r * hown));
        }
      }
      bar_arrive(b1B);
      bar_wait(b1A, 32 * (t + 1));               // rhA ready; fill was P1B
      pf_hc = pf_hn;
      // ---- P2A ----
      {
        const u16* ra = (lan15 < 8) ? (rhAq + bufR + rowoff) : (deadp + rowoff);
        u32x4 rl[4];
#pragma unroll
        for (int ks = 0; ks < 4; ++ks) rl[ks] = ld16(ra + kw + ks * 32 + ke8);
        waitv0();
        f32x4 a2 = z4;
#pragma unroll
        for (int ks = 0; ks < 4; ++ks)
          a2 = MFMA16(__builtin_bit_cast(s16x8, rl[ks]), whh[ks], a2);
        *(f32x4*)(red + ROFF(wave, lan15, lanhi * 4)) = a2;
        __syncthreads();
        if (isA) {
          float wp = upk<GXBF>(pf_hc);
#pragma unroll
          for (int w = 0; w < 4; ++w) wp += red[ROFF(w, col - c0, ob)];
          float pre = fminf(15.f, fmaxf(-15.f, wp));
          float e = __expf(-2.f * pre);
          float ht = (1.f - e) / (1.f + e);
          hn = (1.f - zg) * hown + zg * ht;
          hown = hn;
          u16 hv = (u16)f2bf(hn);
          st2(hbAq + bufW + ob * 512 + col, hv);
          st2c(ys0 + ((size_t)gb * 512 + t) * 512 + col, hv);
        }
      }
      bar_arrive(b2A);
      if (t == 511 && isA) finals[(size_t)(gb * 2 + 0) * 512 + col] = hn;
      bar_wait(b1B, 32 * (t + 1));               // rhB ready; fill was P2A
      // ---- P2B ----
      {
        const u16* rb = (lan15 >= 8) ? (rhBq + bufR + rowoffB) : (deadp + rowoff);
        u32x4 rl[4];
#pragma unroll
        for (int ks = 0; ks < 4; ++ks) rl[ks] = ld16(rb + kw + ks * 32 + ke8);
        waitv0();
        f32x4 a2 = z4;
#pragma unroll
        for (int ks = 0; ks < 4; ++ks)
          a2 = MFMA16(__builtin_bit_cast(s16x8, rl[ks]), whh[ks], a2);
        *(f32x4*)(red + ROFF(wave, lan15, lanhi * 4)) = a2;
        __syncthreads();
        if (!isA) {
          float wp = upk<GXBF>(pf_hc);
#pragma unroll
          for (int w = 0; w < 4; ++w) wp += red[ROFF(w, col - c0, ob)];
          float pre = fminf(15.f, fmaxf(-15.f, wp));
          float e = __expf(-2.f * pre);
          float ht = (1.f - e) / (1.f + e);
          hn = (1.f - zg) * hown + zg * ht;
          hown = hn;
          u16 hv = (u16)f2bf(hn);
          st2(hbBq + bufW + (ob - 8) * 512 + col, hv);
          st2c(ys0 + ((size_t)gb * 512 + t) * 512 + col, hv);
        }
      }
      bar_arrive(b2B);
      if (t == 511 && !isA) finals[(size_t)(gb * 2 + 0) * 512 + col] = hn;
      if (t != 511) {
        issue_pf(t + 1);                         // gap fill for wait(b2A)
        bar_wait(b2A, 32 * (t + 1));             // hbA(t+1) ready next iter
      }
    }
    // post-loop: confirm final b2B, release last prog steps
    bar_wait(b2B, 32 * 512);
    if (tid == 0 && slot == 0)
      __hip_atomic_fetch_add(prog, 1, __ATOMIC_RELAXED, __HIP_MEMORY_SCOPE_AGENT);
  } else {
    // ======================= consumer (layer 1, fused input proj) =======================
    s16x8 w1rz[2][4], w1h[4];
#pragma unroll
    for (int g = 0; g < 2; ++g)
#pragma unroll
      for (int ks = 0; ks < 4; ++ks)
        w1rz[g][ks] = *(const s16x8*)(WTl + ((size_t)(g * 512 + c0 + lan15)) * 1024 + kw + ks * 32 + ke8);
#pragma unroll
    for (int ks = 0; ks < 4; ++ks)
      w1h[ks] = *(const s16x8*)(WTl + ((size_t)(1024 + c0 + lan15)) * 1024 + kw + ks * 32 + ke8);
    const float brv = br[512 + col], bzv = bz[512 + col], bhv = bh[512 + col];

    u32x4 yl[4];
    float zg = 0.f, w1c = 0.f, hn = 0.f;

    if (tid == 0) {                              // wait ys0(0)
      int pv, it = 0;
      do {
        pv = __hip_atomic_load(prog, __ATOMIC_RELAXED, __HIP_MEMORY_SCOPE_AGENT);
        if (pv > 0) break;
        __builtin_amdgcn_s_sleep(2);
      } while (++it < (1 << 22));
      s_prog = pv;
    }
    __syncthreads();
    __builtin_amdgcn_sched_barrier(0);
#pragma unroll
    for (int ks = 0; ks < 4; ++ks)
      yl[ks] = ld16c(ys0 + ((size_t)(q * 16 + lan15) * 512 + 0) * 512 + kw + ks * 32 + ke8);

    for (int t = 0; t < 512; ++t) {
      const int bufR = (t & 1) * 4096, bufW = ((t + 1) & 1) * 4096;
      // ---- P1A: r,z AND ys0@W1h for half A ----
      {
        const u16* ha = (lan15 < 8) ? (hbAq + bufR + rowoff) : (deadp + rowoff);
        u32x4 hl[4];
#pragma unroll
        for (int ks = 0; ks < 4; ++ks) hl[ks] = ld16(ha + kw + ks * 32 + ke8);
        waitv0();                                // hl + yl(t) retired
        f32x4 a0 = z4, a1 = z4, a2 = z4;
#pragma unroll
        for (int ks = 0; ks < 4; ++ks) {
          s16x8 ah = __builtin_bit_cast(s16x8, hl[ks]);
          s16x8 ay = __builtin_bit_cast(s16x8, yl[ks]);
          a0 = MFMA16(ah, wrz[0][ks], a0);
          a0 = MFMA16(ay, w1rz[0][ks], a0);
          a1 = MFMA16(ah, wrz[1][ks], a1);
          a1 = MFMA16(ay, w1rz[1][ks], a1);
          a2 = MFMA16(ay, w1h[ks], a2);
        }
        *(f32x4*)(red + ROFF(wave, lan15, lanhi * 4)) = a0;
        *(f32x4*)(red + ROFF(wave, 16 + lan15, lanhi * 4)) = a1;
        *(f32x4*)(red + ROFF(wave, 32 + lan15, lanhi * 4)) = a2;
        __syncthreads();
        if (isA) {
          float rp = brv, zp = bzv, wc = 0.f;
#pragma unroll
          for (int w = 0; w < 4; ++w) {
            rp += red[ROFF(w, col - c0, ob)];
            zp += red[ROFF(w, 16 + (col - c0), ob)];
            wc += red[ROFF(w, 32 + (col - c0), ob)];
          }
          float r = 1.f / (1.f + __expf(-rp));
          zg = 1.f / (1.f + __expf(-zp));
          w1c = wc;
          st2(rhAq + bufR + ob * 512 + col, (u16)f2bf(r * hown));
        }
      }
      bar_arrive(b1A);
      if (t > 0) bar_wait(b2B, 32 * t);          // hbB(t) ready; fill was P1A
      // ---- P1B ----
      {
        const u16* hbp = (lan15 >= 8) ? (hbBq + bufR + rowoffB) : (deadp + rowoff);
        u32x4 hl[4];
#pragma unroll
        for (int ks = 0; ks < 4; ++ks) hl[ks] = ld16(hbp + kw + ks * 32 + ke8);
        waitv0();
        f32x4 a0 = z4, a1 = z4, a2 = z4;
#pragma unroll
        for (int ks = 0; ks < 4; ++ks) {
          s16x8 ah = __builtin_bit_cast(s16x8, hl[ks]);
          s16x8 ay = __builtin_bit_cast(s16x8, yl[ks]);
          a0 = MFMA16(ah, wrz[0][ks], a0);
          a0 = MFMA16(ay, w1rz[0][ks], a0);
          a1 = MFMA16(ah, wrz[1][ks], a1);
          a1 = MFMA16(ay, w1rz[1][ks], a1);
          a2 = MFMA16(ay, w1h[ks], a2);
        }
        *(f32x4*)(red + ROFF(wave, lan15, lanhi * 4)) = a0;
        *(f32x4*)(red + ROFF(wave, 16 + lan15, lanhi * 4)) = a1;
        *(f32x4*)(red + ROFF(wave, 32 + lan15, lanhi * 4)) = a2;
        __syncthreads();
        if (!isA) {
          float rp = brv, zp = bzv, wc = 0.f;
#pragma unroll
          for (int w = 0; w < 4; ++w) {
            rp += red[ROFF(w, col - c0, ob)];
            zp += red[ROFF(w, 16 + (col - c0), ob)];
            wc += red[ROFF(w, 32 + (col - c0), ob)];
          }
          float r = 1.f / (1.f + __expf(-rp));
          zg = 1.f / (1.f + __expf(-zp));
          w1c = wc;
          st2(rhBq + bufR + (ob - 8) * 512 + col, (u16)f2bf(r * hown));
        }
      }
      bar_arrive(b1B);
      bar_wait(b1A, 32 * (t + 1));               // rhA ready; fill was P1B
      // ---- P2A ----
      {
        const u16* ra = (lan15 < 8) ? (rhAq + bufR + rowoff) : (deadp + rowoff);
        u32x4 rl[4];
#pragma unroll
        for (int ks = 0; ks < 4; ++ks) rl[ks] = ld16(ra + kw + ks * 32 + ke8);
        waitv0();
        f32x4 a3 = z4;
#pragma unroll
        for (int ks = 0; ks < 4; ++ks)
          a3 = MFMA16(__builtin_bit_cast(s16x8, rl[ks]), whh[ks], a3);
        *(f32x4*)(red + ROFF(wave, lan15, lanhi * 4)) = a3;
        __syncthreads();
        if (isA) {
          float wp = bhv + w1c;
#pragma unroll
          for (int w = 0; w < 4; ++w) wp += red[ROFF(w, col - c0, ob)];
          float pre = fminf(15.f, fmaxf(-15.f, wp));
          float e = __expf(-2.f * pre);
          float ht = (1.f - e) / (1.f + e);
          hn = (1.f - zg) * hown + zg * ht;
          hown = hn;
          st2(hbAq + bufW + ob * 512 + col, (u16)f2bf(hn));
        }
      }
      bar_arrive(b2A);
      if (isA) {                                 // gap fill for wait(b1B)
        st4(out_f32 + ((size_t)gb * 512 + t) * 512 + col, __builtin_bit_cast(uint, hn));
        if (t == 511) finals[(size_t)(gb * 2 + 1) * 512 + col] = hn;
      }
      bar_wait(b1B, 32 * (t + 1));               // rhB ready
      // ---- P2B ----
      {
        const u16* rb = (lan15 >= 8) ? (rhBq + bufR + rowoffB) : (deadp + rowoff);
        u32x4 rl[4];
#pragma unroll
        for (int ks = 0; ks < 4; ++ks) rl[ks] = ld16(rb + kw + ks * 32 + ke8);
        waitv0();
        f32x4 a3 = z4;
#pragma unroll
        for (int ks = 0; ks < 4; ++ks)
          a3 = MFMA16(__builtin_bit_cast(s16x8, rl[ks]), whh[ks], a3);
        *(f32x4*)(red + ROFF(wave, lan15, lanhi * 4)) = a3;
        __syncthreads();
        if (!isA) {
          float wp = bhv + w1c;
#pragma unroll
          for (int w = 0; w < 4; ++w) wp += red[ROFF(w, col - c0, ob)];
          float pre = fminf(15.f, fmaxf(-15.f, wp));
          float e = __expf(-2.f * pre);
          float ht = (1.f - e) / (1.f + e);
          hn = (1.f - zg) * hown + zg * ht;
          hown = hn;
          st2(hbBq + bufW + (ob - 8) * 512 + col, (u16)f2bf(hn));
        }
      }
      bar_arrive(b2B);
      // gap fill for wait(b2A): B outputs + yl(t+1) prefetch (prog-gated)
      if (!isA) {
        st4(out_f32 + ((size_t)gb * 512 + t) * 512 + col, __builtin_bit_cast(uint, hn));
        if (t == 511) finals[(size_t)(gb * 2 + 1) * 512 + col] = hn;
      }
      if (t != 511) {
        if (s_prog < t + 2) {
          if (tid == 0) {
            int pv, it = 0;
            do {
              pv = __hip_atomic_load(prog, __ATOMIC_RELAXED, __HIP_MEMORY_SCOPE_AGENT);
              if (pv >= t + 2) break;
              __builtin_amdgcn_s_sleep(2);
            } while (++it < (1 << 22));
            s_prog = pv;
          }
          __syncthreads();
        }
#pragma unroll
        for (int ks = 0; ks < 4; ++ks)
          yl[ks] = ld16c(ys0 + ((size_t)(q * 16 + lan15) * 512 + (t + 1)) * 512 + kw + ks * 32 + ke8);
        bar_wait(b2A, 32 * (t + 1));             // hbA(t+1) ready next iter
      }
    }
  }
}

template <int GXBF>
static void run_all(const float* x, const float* h, const float* Wr, const float* br,
                    const float* Wz, const float* bz, const float* Wh, const float* bh,
                    float* out, char* ws, hipStream_t stream) {
  int* sync  = (int*)(ws + OFF_SYNC);
  u16* hbA   = (u16*)(ws + OFF_HBA);
  u16* hbB   = (u16*)(ws + OFF_HBB);
  u16* rhA   = (u16*)(ws + OFF_RHA);
  u16* rhB   = (u16*)(ws + OFF_RHB);
  u16* WT    = (u16*)(ws + OFF_WT);
  u16* ys0   = (u16*)(ws + OFF_YS0);
  void* gx   = (void*)(ws + OFF_GX);
  float* finals = out + 16777216;

  init_kernel<<<64, 256, 0, stream>>>(h, hbA, hbB, sync);
  convert_w_kernel<<<12288, 256, 0, stream>>>(Wr, Wz, Wh, WT);
  proj_kernel<GXBF><<<3072, 256, 0, stream>>>(x, WT, br, bz, bh, gx);
  gru_pipe<GXBF><<<256, 256, 0, stream>>>(gx, WT, h, hbA, hbB, rhA, rhB, ys0,
                                          br, bz, bh, out, finals, sync);
}

extern "C" void kernel_launch(void* const* d_in, const int* in_sizes, int n_in,
                              void* d_out, int out_size, void* d_ws, size_t ws_size,
                              hipStream_t stream) {
  const float* x  = (const float*)d_in[0];
  const float* h  = (const float*)d_in[1];
  const float* Wr = (const float*)d_in[2];
  const float* br = (const float*)d_in[3];
  const float* Wz = (const float*)d_in[4];
  const float* bz = (const float*)d_in[5];
  const float* Wh = (const float*)d_in[6];
  const float* bh = (const float*)d_in[7];
  float* out = (float*)d_out;
  char* ws = (char*)d_ws;

  const size_t need_f32 = OFF_GX + GX_ELEMS * 4;   // 241,704,960 B (230.5 MiB)
  const size_t need_bf  = OFF_GX + GX_ELEMS * 2;   // 141,041,664 B (134.5 MiB)

  if (ws_size >= need_f32) {
    run_all<0>(x, h, Wr, br, Wz, bz, Wh, bh, out, ws, stream);
  } else if (ws_size >= need_bf) {
    run_all<1>(x, h, Wr, br, Wz, bz, Wh, bh, out, ws, stream);
  } else {
    sentinel_kernel<<<1, 64, 0, stream>>>(out, (float)ws_size);
  }
}

// Round 17
// 2358.953 us; speedup vs baseline: 1.3394x; 1.3394x over previous
//
#include <hip/hip_runtime.h>

typedef unsigned int uint;
typedef unsigned short u16;
typedef short s16x8 __attribute__((ext_vector_type(8)));
typedef float f32x4 __attribute__((ext_vector_type(4)));
typedef uint u32x4 __attribute__((ext_vector_type(4)));

#define MFMA16(a, b, c) __builtin_amdgcn_mfma_f32_16x16x32_bf16((a), (b), (c), 0, 0, 0)

// ---- problem constants ----
// B=64, S=512, D=512, H=512, L=2
// sync region (8704 ints = 34816 B, reserve 36864):
//   [xcc*32]    : per-XCD barrier counters (own 128B line each)
//   [256..263]  : claim[8] (L3 agent atomics)
//   [320+q*32]  : prog[q] (own 128B line each, L3 agent atomics)
// hb/rhb: 4-deep ROTATING buffers (buf = t&3) — R14-proven stale-L1 fix.
// THIS ROUND: 16 worker WGs/XCD (32 cols each) instead of 32 — halves barrier
// arrival traffic + straggler population; per-WG compute stays negligible.
static const size_t OFF_SYNC = 0;                      // 36864 B
static const size_t OFF_HB   = 36864;                  // [2][4][4 bufs][16][512] bf16 = 524288
static const size_t OFF_RHB  = 561152;                 // [2][4][4 bufs][16][512] bf16 = 524288
static const size_t OFF_WT   = 1085440;                // [2][3][512][1024] bf16 = 6291456
static const size_t OFF_YS0  = 7376896;                // [64][512][512] bf16 = 33554432
static const size_t OFF_GX   = 40931328;               // [512][64][1536] f32 or bf16
static const size_t GX_ELEMS = (size_t)512 * 64 * 1536;

__device__ __forceinline__ short f2bf(float x) {       // RNE float->bf16
  uint u = __builtin_bit_cast(uint, x);
  u = u + 0x7fffu + ((u >> 16) & 1u);
  return (short)(u >> 16);
}
__device__ __forceinline__ float bf2f(u16 v) {
  uint u = ((uint)v) << 16;
  return __builtin_bit_cast(float, u);
}

// ---- raw memory ops ----
__device__ __forceinline__ u32x4 ld16(const void* p) {          // plain: L1 + local L2
  u32x4 r;
  asm volatile("global_load_dwordx4 %0, %1, off" : "=v"(r) : "v"(p));
  return r;
}
__device__ __forceinline__ uint ld4u(const void* p) {
  uint r;
  asm volatile("global_load_dword %0, %1, off" : "=v"(r) : "v"(p));
  return r;
}
__device__ __forceinline__ uint ld2x(const void* p) {
  uint r;
  asm volatile("global_load_ushort %0, %1, off" : "=v"(r) : "v"(p));
  return r;
}
__device__ __forceinline__ void st4(void* p, uint v) {
  asm volatile("global_store_dword %0, %1, off" :: "v"(p), "v"(v));
}
__device__ __forceinline__ void st2(void* p, u16 v) {
  uint x = v;
  asm volatile("global_store_short %0, %1, off" :: "v"(p), "v"(x));
}
// cross-XCD coherent (system scope, served at L3): sc0 sc1 — R3/R9-proven combo
__device__ __forceinline__ u32x4 ld16c(const void* p) {
  u32x4 r;
  asm volatile("global_load_dwordx4 %0, %1, off sc0 sc1" : "=v"(r) : "v"(p));
  return r;
}
__device__ __forceinline__ void st2c(void* p, u16 v) {
  uint x = v;
  asm volatile("global_store_short %0, %1, off sc0 sc1" :: "v"(p), "v"(x));
}
__device__ __forceinline__ void waitv0() {
  asm volatile("s_waitcnt vmcnt(0)" ::: "memory");
  __builtin_amdgcn_sched_barrier(0);   // rule #18
}

template <int GXBF>
__device__ __forceinline__ float upk(uint v) {
  if constexpr (GXBF) return bf2f((u16)v);
  else return __builtin_bit_cast(float, v);
}

// ---------------- sentinel ----------------
__global__ void sentinel_kernel(float* __restrict__ out, float v) {
  out[threadIdx.x] = v;
}

// ---------------- init: sync words, h0 -> bf16 quarter layout (buf 0 of 4) ----------------
__global__ void init_kernel(const float* __restrict__ h_in, u16* __restrict__ hb,
                            int* __restrict__ sync) {
  int idx = blockIdx.x * 256 + threadIdx.x;
  if (idx < 8704) sync[idx] = 0;
  for (int i = idx; i < 2 * 64 * 512; i += gridDim.x * 256) {
    int l = i >> 15, b = (i >> 9) & 63, c = i & 511;
    int q = b >> 4, ob = b & 15;
    hb[((l * 4 + q) * 4 + 0) * 8192 + ob * 512 + c] = (u16)f2bf(h_in[(b * 2 + l) * 512 + c]);
  }
}

// ---------------- W (L,1024,512) f32 -> WT[l][g][n][k] bf16 (k-major) ----------------
__global__ void convert_w_kernel(const float* __restrict__ Wr, const float* __restrict__ Wz,
                                 const float* __restrict__ Wh, u16* __restrict__ WT) {
  int idx = blockIdx.x * 256 + threadIdx.x;       // 6*512*1024 = 3145728 total
  int n = idx & 511, k = (idx >> 9) & 1023, lg = idx >> 19;
  int l = (lg >= 3) ? 1 : 0, g = lg - l * 3;
  const float* W = (g == 0 ? Wr : (g == 1 ? Wz : Wh)) + (size_t)l * 1024 * 512;
  WT[((size_t)lg * 512 + n) * 1024 + k] = (u16)f2bf(W[k * 512 + n]);
}

// ---------------- input projection GEMM (layer 0 only) ----------------
template <int GXBF>
__global__ __launch_bounds__(256) void proj_kernel(
    const float* __restrict__ A, const u16* __restrict__ WT,
    const float* __restrict__ br, const float* __restrict__ bz, const float* __restrict__ bh,
    void* __restrict__ gx) {
  __shared__ u16 Alds[128 * 64];
  __shared__ u16 Blds[128 * 64];
  const int tid = threadIdx.x;
  const int wave = tid >> 6, lane = tid & 63;
  const int lan15 = lane & 15, lanhi = lane >> 4;
  const int mb = blockIdx.x & 255, nb = blockIdx.x >> 8;
  const int m0 = mb * 128, n0 = nb * 128;
  const int wm = (wave >> 1) * 64, wn = (wave & 1) * 64;

  const f32x4 z4 = {0.f, 0.f, 0.f, 0.f};
  f32x4 acc[4][4];
#pragma unroll
  for (int i = 0; i < 4; ++i)
#pragma unroll
    for (int j = 0; j < 4; ++j) acc[i][j] = z4;

  for (int kb = 0; kb < 512; kb += 64) {
    __syncthreads();
#pragma unroll
    for (int p = 0; p < 4; ++p) {        // stage+convert A tile 128x64 (XOR-swizzled 16B slots)
      int idx = p * 256 + tid;
      int row = idx >> 3, slot = idx & 7;
      const float* src = A + (size_t)(m0 + row) * 512 + kb + slot * 8;
      float4 v0 = *(const float4*)src;
      float4 v1 = *(const float4*)(src + 4);
      u16 tmp[8] = {(u16)f2bf(v0.x), (u16)f2bf(v0.y), (u16)f2bf(v0.z), (u16)f2bf(v0.w),
                    (u16)f2bf(v1.x), (u16)f2bf(v1.y), (u16)f2bf(v1.z), (u16)f2bf(v1.w)};
      *(uint4*)((char*)Alds + row * 128 + ((slot ^ (row & 7)) * 16)) = *(uint4*)tmp;
    }
#pragma unroll
    for (int p = 0; p < 4; ++p) {        // stage B tile 128x64 from WT (n-major rows)
      int idx = p * 256 + tid;
      int row = idx >> 3, slot = idx & 7;
      int ng = n0 + row, g = ng >> 9, nc = ng & 511;
      uint4 v = *(const uint4*)(WT + ((size_t)g * 512 + nc) * 1024 + kb + slot * 8);
      *(uint4*)((char*)Blds + row * 128 + ((slot ^ (row & 7)) * 16)) = v;
    }
    __syncthreads();
#pragma unroll
    for (int ks = 0; ks < 2; ++ks) {
      s16x8 af[4], bfr[4];
#pragma unroll
      for (int f = 0; f < 4; ++f) {
        int rowA = wm + f * 16 + lan15;
        af[f] = *(const s16x8*)((const char*)Alds + rowA * 128 + (((ks * 4 + lanhi) ^ (rowA & 7)) * 16));
        int rowB = wn + f * 16 + lan15;
        bfr[f] = *(const s16x8*)((const char*)Blds + rowB * 128 + (((ks * 4 + lanhi) ^ (rowB & 7)) * 16));
      }
#pragma unroll
      for (int mf = 0; mf < 4; ++mf)
#pragma unroll
        for (int nf = 0; nf < 4; ++nf)
          acc[mf][nf] = MFMA16(af[mf], bfr[nf], acc[mf][nf]);
    }
  }
#pragma unroll
  for (int nf = 0; nf < 4; ++nf) {
    int n = n0 + wn + nf * 16 + lan15;
    int g = n >> 9, nc = n & 511;
    float bias = (g == 0 ? br[nc] : (g == 1 ? bz[nc] : bh[nc]));
#pragma unroll
    for (int mf = 0; mf < 4; ++mf) {
#pragma unroll
      for (int q = 0; q < 4; ++q) {
        int m = m0 + wm + mf * 16 + lanhi * 4 + q;
        int s = m & 511, b = m >> 9;
        size_t e = (size_t)(s * 64 + b) * 1536 + n;
        float v = acc[mf][nf][q] + bias;
        if constexpr (GXBF) ((u16*)gx)[e] = (u16)f2bf(v);
        else ((float*)gx)[e] = v;
      }
    }
  }
}

// ---------------- XCD-local barrier: L2-executed atomics (R6-R14 proven) ----------------
__device__ __forceinline__ void gbarA(int* bar, int target) {
  asm volatile("s_waitcnt vmcnt(0)" ::: "memory");
  __syncthreads();
  if (threadIdx.x == 0) {
    int one = 1;
    asm volatile("global_atomic_add %0, %1, off" :: "v"(bar), "v"(one) : "memory");
    int v, zero = 0, iter = 0;
    do {
      asm volatile("global_atomic_add %0, %1, %2, off sc0\n\ts_waitcnt vmcnt(0)"
                   : "=v"(v) : "v"(bar), "v"(zero) : "memory");
      if (v >= target) break;
      __builtin_amdgcn_s_sleep(1);
    } while (++iter < (1 << 17));      // watchdog
  }
  __syncthreads();
  __builtin_amdgcn_sched_barrier(0);
}
__device__ __forceinline__ void bar_arrive(int* bar) {
  asm volatile("s_waitcnt vmcnt(0)" ::: "memory");
  __syncthreads();
  if (threadIdx.x == 0) {
    int one = 1;
    asm volatile("global_atomic_add %0, %1, off" :: "v"(bar), "v"(one) : "memory");
  }
}
__device__ __forceinline__ void bar_wait(int* bar, int target) {
  if (threadIdx.x == 0) {
    int v, zero = 0, iter = 0;
    do {
      asm volatile("global_atomic_add %0, %1, %2, off sc0\n\ts_waitcnt vmcnt(0)"
                   : "=v"(v) : "v"(bar), "v"(zero) : "memory");
      if (v >= target) break;
      __builtin_amdgcn_s_sleep(1);
    } while (++iter < (1 << 17));      // watchdog
  }
  __syncthreads();
  __builtin_amdgcn_sched_barrier(0);
}

// red: [4 waves][96 cols][pad 20] f32 (blocks: r 0..31, z 32..63, w1h 64..95)
__device__ __forceinline__ int ROFF(int w, int c, int b) {
  return (w * 96 + c) * 20 + b;
}

// ---------------- persistent pipelined GRU: 8 XCDs = 2 layers x 4 batch-quarters ----------
// grid=256, 84KB LDS -> 1 WG/CU -> 32 WGs/XCD arrive; slots 0..15 WORK (32 cols each),
// slots 16..31 exit. Barrier participants halved vs R14. All else R14-proven:
// 2 barriers/step, 4-deep rotation, consumer gap yl-prefetch, prog-gated handoff.
template <int GXBF>
__global__ __launch_bounds__(256, 1) void gru_pipe(
    const void* __restrict__ gx,     // [512][64][1536] layer-0 gates
    const u16* __restrict__ WT,      // [2][3][512][1024]
    const float* __restrict__ h_in,  // [64][2][512]
    u16* __restrict__ hb,            // [2][4][4 bufs][16][512]
    u16* __restrict__ rhb,           // [2][4][4 bufs][16][512]
    u16* __restrict__ ys0,           // [64][512][512] bf16 (L0 -> L1 via L3)
    const float* __restrict__ br, const float* __restrict__ bz, const float* __restrict__ bh,
    float* __restrict__ out_f32,     // d_out [64][512][512] f32
    float* __restrict__ finals,      // d_out + B*S*H  [64][2][512]
    int* __restrict__ sync) {
  __shared__ float red[21504];       // 84 KiB: forces 1 WG/CU
  __shared__ int s_pack, s_prog;

  if (threadIdx.x == 0) {
    int xcc;
    asm volatile("s_getreg_b32 %0, hwreg(HW_REG_XCC_ID)" : "=s"(xcc));
    xcc &= 7;
    int slot = __hip_atomic_fetch_add(&sync[256 + xcc], 1, __ATOMIC_RELAXED,
                                      __HIP_MEMORY_SCOPE_AGENT);
    s_pack = slot | (xcc << 8);
    s_prog = 0;
  }
  __syncthreads();
  const int slot = s_pack & 255;
  const int xcc  = s_pack >> 8;
  if (slot >= 16) return;            // 16 workers per XCD

  const int l = (xcc >> 2) & 1, q = xcc & 3;
  int* bar  = sync + xcc * 32;
  int* prog = sync + 320 + q * 32;

  const int tid = threadIdx.x;
  const int wave = tid >> 6, lane = tid & 63;
  const int lan15 = lane & 15, lanhi = lane >> 4;
  const int c0 = slot * 32;          // owned columns [c0, c0+32)
  const int kw = wave * 128;         // K-split per wave
  const int ke8 = lanhi * 8;
  const int ob = tid >> 4;           // local batch 0..15
  const int ci = tid & 15;
  const int col0 = c0 + ci, col1 = c0 + 16 + ci;   // 2 owned cols per thread
  const int gb = q * 16 + ob;        // global batch
  const int ES = GXBF ? 2 : 4;
  const f32x4 z4 = {0.f, 0.f, 0.f, 0.f};

  const u16* WTl = WT + (size_t)l * 3 * 512 * 1024;
  u16* hbq  = hb  + (size_t)(l * 4 + q) * 4 * 8192;   // + (t&3)*8192
  u16* rhbq = rhb + (size_t)(l * 4 + q) * 4 * 8192;

  // recurrent weights: [gate r/z][tile 0/1][ks]
  s16x8 wrz[2][2][4], whh[2][4];
#pragma unroll
  for (int g = 0; g < 2; ++g)
#pragma unroll
    for (int j = 0; j < 2; ++j)
#pragma unroll
      for (int ks = 0; ks < 4; ++ks)
        wrz[g][j][ks] = *(const s16x8*)(WTl + ((size_t)(g * 512 + c0 + j * 16 + lan15)) * 1024 + 512 + kw + ks * 32 + ke8);
#pragma unroll
  for (int j = 0; j < 2; ++j)
#pragma unroll
    for (int ks = 0; ks < 4; ++ks)
      whh[j][ks] = *(const s16x8*)(WTl + ((size_t)(1024 + c0 + j * 16 + lan15)) * 1024 + 512 + kw + ks * 32 + ke8);

  float hown0 = h_in[(gb * 2 + l) * 512 + col0];
  float hown1 = h_in[(gb * 2 + l) * 512 + col1];

  if (l == 0) {
    // ================= producer quarter (layer 0) =================
    uint pf_r0 = 0, pf_r1 = 0, pf_z0 = 0, pf_z1 = 0, pf_hn0 = 0, pf_hn1 = 0, pf_hc0 = 0, pf_hc1 = 0;
    auto issue_pf = [&](int tp) {
      const char* gq = (const char*)gx + ((size_t)(tp * 64 + gb) * 1536 + col0) * ES;
      if constexpr (GXBF) {
        pf_r0 = ld2x(gq);            pf_r1 = ld2x(gq + 32);
        pf_z0 = ld2x(gq + 1024);     pf_z1 = ld2x(gq + 1056);
        pf_hn0 = ld2x(gq + 2048);    pf_hn1 = ld2x(gq + 2080);
      } else {
        pf_r0 = ld4u(gq);            pf_r1 = ld4u(gq + 64);
        pf_z0 = ld4u(gq + 2048);     pf_z1 = ld4u(gq + 2112);
        pf_hn0 = ld4u(gq + 4096);    pf_hn1 = ld4u(gq + 4160);
      }
    };
    issue_pf(0);

    for (int t = 0; t < 512; ++t) {
      const u16* hc = hbq + (t & 3) * 8192;
      u16* rhc = rhbq + (t & 3) * 8192;
      u32x4 hl[4];
#pragma unroll
      for (int ks = 0; ks < 4; ++ks)
        hl[ks] = ld16(hc + lan15 * 512 + kw + ks * 32 + ke8);
      waitv0();                                  // hl + pf(t) retired
      f32x4 ar0 = z4, ar1 = z4, az0 = z4, az1 = z4;
#pragma unroll
      for (int ks = 0; ks < 4; ++ks) {
        s16x8 ah = __builtin_bit_cast(s16x8, hl[ks]);
        ar0 = MFMA16(ah, wrz[0][0][ks], ar0);
        ar1 = MFMA16(ah, wrz[0][1][ks], ar1);
        az0 = MFMA16(ah, wrz[1][0][ks], az0);
        az1 = MFMA16(ah, wrz[1][1][ks], az1);
      }
      *(f32x4*)(red + ROFF(wave, lan15, lanhi * 4)) = ar0;
      *(f32x4*)(red + ROFF(wave, 16 + lan15, lanhi * 4)) = ar1;
      *(f32x4*)(red + ROFF(wave, 32 + lan15, lanhi * 4)) = az0;
      *(f32x4*)(red + ROFF(wave, 48 + lan15, lanhi * 4)) = az1;
      __syncthreads();
      float zg0, zg1;
      {
        float rp0 = upk<GXBF>(pf_r0), zp0 = upk<GXBF>(pf_z0);
        float rp1 = upk<GXBF>(pf_r1), zp1 = upk<GXBF>(pf_z1);
#pragma unroll
        for (int w = 0; w < 4; ++w) {
          rp0 += red[ROFF(w, ci, ob)];
          rp1 += red[ROFF(w, 16 + ci, ob)];
          zp0 += red[ROFF(w, 32 + ci, ob)];
          zp1 += red[ROFF(w, 48 + ci, ob)];
        }
        float r0 = 1.f / (1.f + __expf(-rp0));
        float r1 = 1.f / (1.f + __expf(-rp1));
        zg0 = 1.f / (1.f + __expf(-zp0));
        zg1 = 1.f / (1.f + __expf(-zp1));
        st2(rhc + ob * 512 + col0, (u16)f2bf(r0 * hown0));
        st2(rhc + ob * 512 + col1, (u16)f2bf(r1 * hown1));
      }
      gbarA(bar, 16 * (2 * t + 1));
      // phase 2
      pf_hc0 = pf_hn0; pf_hc1 = pf_hn1;
      u32x4 rl[4];
#pragma unroll
      for (int ks = 0; ks < 4; ++ks)
        rl[ks] = ld16(rhc + lan15 * 512 + kw + ks * 32 + ke8);
      issue_pf(t < 511 ? t + 1 : 511);
      asm volatile("s_waitcnt vmcnt(6)" ::: "memory");   // rl done, 6 pf in flight
      __builtin_amdgcn_sched_barrier(0);
      f32x4 ah0 = z4, ah1 = z4;
#pragma unroll
      for (int ks = 0; ks < 4; ++ks) {
        s16x8 av = __builtin_bit_cast(s16x8, rl[ks]);
        ah0 = MFMA16(av, whh[0][ks], ah0);
        ah1 = MFMA16(av, whh[1][ks], ah1);
      }
      *(f32x4*)(red + ROFF(wave, lan15, lanhi * 4)) = ah0;
      *(f32x4*)(red + ROFF(wave, 16 + lan15, lanhi * 4)) = ah1;
      __syncthreads();
      float hn0, hn1;
      {
        float wp0 = upk<GXBF>(pf_hc0), wp1 = upk<GXBF>(pf_hc1);
#pragma unroll
        for (int w = 0; w < 4; ++w) {
          wp0 += red[ROFF(w, ci, ob)];
          wp1 += red[ROFF(w, 16 + ci, ob)];
        }
        float p0 = fminf(15.f, fmaxf(-15.f, wp0));
        float p1 = fminf(15.f, fmaxf(-15.f, wp1));
        float e0 = __expf(-2.f * p0), e1 = __expf(-2.f * p1);
        float t0 = (1.f - e0) / (1.f + e0), t1 = (1.f - e1) / (1.f + e1);
        hn0 = (1.f - zg0) * hown0 + zg0 * t0;
        hn1 = (1.f - zg1) * hown1 + zg1 * t1;
        hown0 = hn0; hown1 = hn1;
        u16 hv0 = (u16)f2bf(hn0), hv1 = (u16)f2bf(hn1);
        u16* hnx = hbq + ((t + 1) & 3) * 8192 + ob * 512;
        st2(hnx + col0, hv0);
        st2(hnx + col1, hv1);
        st2c(ys0 + ((size_t)gb * 512 + t) * 512 + col0, hv0);
        st2c(ys0 + ((size_t)gb * 512 + t) * 512 + col1, hv1);
      }
      gbarA(bar, 16 * (2 * t + 2));              // ALWAYS (t=511 too): gates prog bump
      if (tid == 0 && slot == 0)
        __hip_atomic_fetch_add(prog, 1, __ATOMIC_RELAXED, __HIP_MEMORY_SCOPE_AGENT);
      if (t == 511) {
        finals[(size_t)(gb * 2 + 0) * 512 + col0] = hn0;
        finals[(size_t)(gb * 2 + 0) * 512 + col1] = hn1;
      }
    }
  } else {
    // ================= consumer quarter (layer 1, fused input proj) =================
    s16x8 w1rz[2][2][4], w1h[2][4];
#pragma unroll
    for (int g = 0; g < 2; ++g)
#pragma unroll
      for (int j = 0; j < 2; ++j)
#pragma unroll
        for (int ks = 0; ks < 4; ++ks)
          w1rz[g][j][ks] = *(const s16x8*)(WTl + ((size_t)(g * 512 + c0 + j * 16 + lan15)) * 1024 + kw + ks * 32 + ke8);
#pragma unroll
    for (int j = 0; j < 2; ++j)
#pragma unroll
      for (int ks = 0; ks < 4; ++ks)
        w1h[j][ks] = *(const s16x8*)(WTl + ((size_t)(1024 + c0 + j * 16 + lan15)) * 1024 + kw + ks * 32 + ke8);
    const float brv0 = br[512 + col0], bzv0 = bz[512 + col0], bhv0 = bh[512 + col0];
    const float brv1 = br[512 + col1], bzv1 = bz[512 + col1], bhv1 = bh[512 + col1];

    u32x4 yl[4];                                 // ys0 fragments (single buffer)
    if (tid == 0) {                              // wait ys0(0)
      int pv, it = 0;
      do {
        pv = __hip_atomic_load(prog, __ATOMIC_RELAXED, __HIP_MEMORY_SCOPE_AGENT);
        if (pv > 0) break;
        __builtin_amdgcn_s_sleep(2);
      } while (++it < (1 << 22));
      s_prog = pv;
    }
    __syncthreads();
    __builtin_amdgcn_sched_barrier(0);
#pragma unroll
    for (int ks = 0; ks < 4; ++ks)
      yl[ks] = ld16c(ys0 + ((size_t)(q * 16 + lan15) * 512 + 0) * 512 + kw + ks * 32 + ke8);

    for (int t = 0; t < 512; ++t) {
      const u16* hc = hbq + (t & 3) * 8192;
      u16* rhc = rhbq + (t & 3) * 8192;
      u32x4 hl[4];
#pragma unroll
      for (int ks = 0; ks < 4; ++ks)
        hl[ks] = ld16(hc + lan15 * 512 + kw + ks * 32 + ke8);
      waitv0();                                  // hl + prefetched yl retired
      // phase 1: r,z (h + ys0) AND ys0@W1h, 2 tiles each
      f32x4 ar0 = z4, ar1 = z4, az0 = z4, az1 = z4, aw0 = z4, aw1 = z4;
#pragma unroll
      for (int ks = 0; ks < 4; ++ks) {
        s16x8 ah = __builtin_bit_cast(s16x8, hl[ks]);
        s16x8 ay = __builtin_bit_cast(s16x8, yl[ks]);
        ar0 = MFMA16(ah, wrz[0][0][ks], ar0);
        ar0 = MFMA16(ay, w1rz[0][0][ks], ar0);
        ar1 = MFMA16(ah, wrz[0][1][ks], ar1);
        ar1 = MFMA16(ay, w1rz[0][1][ks], ar1);
        az0 = MFMA16(ah, wrz[1][0][ks], az0);
        az0 = MFMA16(ay, w1rz[1][0][ks], az0);
        az1 = MFMA16(ah, wrz[1][1][ks], az1);
        az1 = MFMA16(ay, w1rz[1][1][ks], az1);
        aw0 = MFMA16(ay, w1h[0][ks], aw0);
        aw1 = MFMA16(ay, w1h[1][ks], aw1);
      }
      *(f32x4*)(red + ROFF(wave, lan15, lanhi * 4)) = ar0;
      *(f32x4*)(red + ROFF(wave, 16 + lan15, lanhi * 4)) = ar1;
      *(f32x4*)(red + ROFF(wave, 32 + lan15, lanhi * 4)) = az0;
      *(f32x4*)(red + ROFF(wave, 48 + lan15, lanhi * 4)) = az1;
      *(f32x4*)(red + ROFF(wave, 64 + lan15, lanhi * 4)) = aw0;
      *(f32x4*)(red + ROFF(wave, 80 + lan15, lanhi * 4)) = aw1;
      __syncthreads();
      float zg0, zg1, w1c0, w1c1;
      {
        float rp0 = brv0, zp0 = bzv0, wc0 = 0.f;
        float rp1 = brv1, zp1 = bzv1, wc1 = 0.f;
#pragma unroll
        for (int w = 0; w < 4; ++w) {
          rp0 += red[ROFF(w, ci, ob)];
          rp1 += red[ROFF(w, 16 + ci, ob)];
          zp0 += red[ROFF(w, 32 + ci, ob)];
          zp1 += red[ROFF(w, 48 + ci, ob)];
          wc0 += red[ROFF(w, 64 + ci, ob)];
          wc1 += red[ROFF(w, 80 + ci, ob)];
        }
        float r0 = 1.f / (1.f + __expf(-rp0));
        float r1 = 1.f / (1.f + __expf(-rp1));
        zg0 = 1.f / (1.f + __expf(-zp0));
        zg1 = 1.f / (1.f + __expf(-zp1));
        w1c0 = wc0; w1c1 = wc1;
        st2(rhc + ob * 512 + col0, (u16)f2bf(r0 * hown0));
        st2(rhc + ob * 512 + col1, (u16)f2bf(r1 * hown1));
      }
      // barrier 1: arrive -> (prog check + yl(t+1) issue in gap) -> wait
      bar_arrive(bar);
      if (t != 511) {
        if (s_prog < t + 2) {
          if (tid == 0) {
            int pv, it = 0;
            do {
              pv = __hip_atomic_load(prog, __ATOMIC_RELAXED, __HIP_MEMORY_SCOPE_AGENT);
              if (pv >= t + 2) break;
              __builtin_amdgcn_s_sleep(2);
            } while (++it < (1 << 22));
            s_prog = pv;
          }
          __syncthreads();
        }
#pragma unroll
        for (int ks = 0; ks < 4; ++ks)
          yl[ks] = ld16c(ys0 + ((size_t)(q * 16 + lan15) * 512 + (t + 1)) * 512 + kw + ks * 32 + ke8);
      }
      bar_wait(bar, 16 * (2 * t + 1));
      // phase 2: (r*h)@Whh only
      u32x4 rl[4];
#pragma unroll
      for (int ks = 0; ks < 4; ++ks)
        rl[ks] = ld16(rhc + lan15 * 512 + kw + ks * 32 + ke8);
      waitv0();                                  // drains rl AND yl(t+1) prefetch
      f32x4 ah0 = z4, ah1 = z4;
#pragma unroll
      for (int ks = 0; ks < 4; ++ks) {
        s16x8 av = __builtin_bit_cast(s16x8, rl[ks]);
        ah0 = MFMA16(av, whh[0][ks], ah0);
        ah1 = MFMA16(av, whh[1][ks], ah1);
      }
      *(f32x4*)(red + ROFF(wave, lan15, lanhi * 4)) = ah0;
      *(f32x4*)(red + ROFF(wave, 16 + lan15, lanhi * 4)) = ah1;
      __syncthreads();
      float hn0, hn1;
      {
        float wp0 = bhv0 + w1c0, wp1 = bhv1 + w1c1;
#pragma unroll
        for (int w = 0; w < 4; ++w) {
          wp0 += red[ROFF(w, ci, ob)];
          wp1 += red[ROFF(w, 16 + ci, ob)];
        }
        float p0 = fminf(15.f, fmaxf(-15.f, wp0));
        float p1 = fminf(15.f, fmaxf(-15.f, wp1));
        float e0 = __expf(-2.f * p0), e1 = __expf(-2.f * p1);
        float t0 = (1.f - e0) / (1.f + e0), t1 = (1.f - e1) / (1.f + e1);
        hn0 = (1.f - zg0) * hown0 + zg0 * t0;
        hn1 = (1.f - zg1) * hown1 + zg1 * t1;
        hown0 = hn0; hown1 = hn1;
        u16* hnx = hbq + ((t + 1) & 3) * 8192 + ob * 512;
        st2(hnx + col0, (u16)f2bf(hn0));
        st2(hnx + col1, (u16)f2bf(hn1));
      }
      // barrier 2: arrive -> output stores in gap -> wait
      if (t != 511) {
        bar_arrive(bar);
        st4(out_f32 + ((size_t)gb * 512 + t) * 512 + col0, __builtin_bit_cast(uint, hn0));
        st4(out_f32 + ((size_t)gb * 512 + t) * 512 + col1, __builtin_bit_cast(uint, hn1));
        bar_wait(bar, 16 * (2 * t + 2));
      } else {
        st4(out_f32 + ((size_t)gb * 512 + t) * 512 + col0, __builtin_bit_cast(uint, hn0));
        st4(out_f32 + ((size_t)gb * 512 + t) * 512 + col1, __builtin_bit_cast(uint, hn1));
        finals[(size_t)(gb * 2 + 1) * 512 + col0] = hn0;
        finals[(size_t)(gb * 2 + 1) * 512 + col1] = hn1;
      }
    }
  }
}

template <int GXBF>
static void run_all(const float* x, const float* h, const float* Wr, const float* br,
                    const float* Wz, const float* bz, const float* Wh, const float* bh,
                    float* out, char* ws, hipStream_t stream) {
  int* sync  = (int*)(ws + OFF_SYNC);
  u16* hbAll = (u16*)(ws + OFF_HB);
  u16* rhb   = (u16*)(ws + OFF_RHB);
  u16* WT    = (u16*)(ws + OFF_WT);
  u16* ys0   = (u16*)(ws + OFF_YS0);
  void* gx   = (void*)(ws + OFF_GX);
  float* finals = out + 16777216;

  init_kernel<<<64, 256, 0, stream>>>(h, hbAll, sync);
  convert_w_kernel<<<12288, 256, 0, stream>>>(Wr, Wz, Wh, WT);
  proj_kernel<GXBF><<<3072, 256, 0, stream>>>(x, WT, br, bz, bh, gx);
  gru_pipe<GXBF><<<256, 256, 0, stream>>>(gx, WT, h, hbAll, rhb, ys0,
                                          br, bz, bh, out, finals, sync);
}

extern "C" void kernel_launch(void* const* d_in, const int* in_sizes, int n_in,
                              void* d_out, int out_size, void* d_ws, size_t ws_size,
                              hipStream_t stream) {
  const float* x  = (const float*)d_in[0];
  const float* h  = (const float*)d_in[1];
  const float* Wr = (const float*)d_in[2];
  const float* br = (const float*)d_in[3];
  const float* Wz = (const float*)d_in[4];
  const float* bz = (const float*)d_in[5];
  const float* Wh = (const float*)d_in[6];
  const float* bh = (const float*)d_in[7];
  float* out = (float*)d_out;
  char* ws = (char*)d_ws;

  const size_t need_f32 = OFF_GX + GX_ELEMS * 4;   // 242,257,920 B (231.0 MiB)
  const size_t need_bf  = OFF_GX + GX_ELEMS * 2;   // 141,594,624 B (135.0 MiB)

  if (ws_size >= need_f32) {
    run_all<0>(x, h, Wr, br, Wz, bz, Wh, bh, out, ws, stream);
  } else if (ws_size >= need_bf) {
    run_all<1>(x, h, Wr, br, Wz, bz, Wh, bh, out, ws, stream);
  } else {
    sentinel_kernel<<<1, 64, 0, stream>>>(out, (float)ws_size);
  }
}